// Round 1
// baseline (537.625 us; speedup 1.0000x reference)
//
#include <hip/hip_runtime.h>
#include <hip/hip_bf16.h>

#define NN 16000
#define EE 256000
#define CC 64
#define AA 10
#define RR 8
#define NC9 9216000      // N*C*9
#define SC_OFF 18432000  // 2*N*C*9

// ---------------- workspace layout (bytes) ----------------
// h:        [N][64] f32                     0          .. 4,096,000
// macc:     [N][18][64] f32 (cm = conv*9+m) 4,096,000  .. 77,824,000
// species:  [N] i32                         77,824,000 .. 77,888,000
// counts:   [N] i32                         77,888,000 .. 77,952,000
// cursor:   [N] i32                         77,952,000 .. 78,016,000
// offsets:  [N+1] i32 (padded)              78,016,000 .. 78,080,256
// edgelist: [E] i32                         78,080,256 .. 79,104,256
#define WS_H        0
#define WS_MACC     4096000
#define WS_SPECIES  77824000
#define WS_COUNTS   77888000
#define WS_CURSOR   77952000
#define WS_OFFSETS  78016000
#define WS_EDGELIST 78080256

__global__ __launch_bounds__(256) void species_kernel(
    const float* __restrict__ attrs, int* __restrict__ species) {
  int i = blockIdx.x * 256 + threadIdx.x;
  if (i >= NN) return;
  const float* p = attrs + (size_t)i * AA;
  int sp = 0;
#pragma unroll
  for (int a = 1; a < AA; ++a)
    if (p[a] > 0.5f) sp = a;
  species[i] = sp;
}

// h = (nf @ W_up)/8 ; sc = (nf . W_skip[:,a,:])/sqrt(640)
__global__ __launch_bounds__(256) void node_kernel(
    const float* __restrict__ nf, const int* __restrict__ species,
    const float* __restrict__ W_up, const float* __restrict__ W_skip,
    float* __restrict__ h, float* __restrict__ out) {
  int wid = __builtin_amdgcn_readfirstlane(threadIdx.x >> 6);
  int lane = threadIdx.x & 63;
  int n = blockIdx.x * 4 + wid;
  int a = species[n];
  const float* nfp = nf + (size_t)n * 64;
  const float* wsk = W_skip + (size_t)a * 64;  // + u*640 + lane
  float hacc = 0.f, sacc = 0.f;
#pragma unroll
  for (int u = 0; u < 64; ++u) {
    float x = nfp[u];  // wave-uniform -> scalar load
    hacc = fmaf(x, W_up[u * 64 + lane], hacc);
    sacc = fmaf(x, wsk[u * 640 + lane], sacc);
  }
  h[(size_t)n * 64 + lane] = hacc * 0.125f;
  out[SC_OFF + (size_t)n * 64 + lane] = sacc * 0.03952847075210474f;
}

__global__ __launch_bounds__(256) void hist_kernel(
    const int* __restrict__ recv, int* __restrict__ counts) {
  int e = blockIdx.x * 256 + threadIdx.x;
  if (e < EE) atomicAdd(&counts[recv[e]], 1);
}

// single-block exclusive scan of counts[N] -> offsets[N+1]
__global__ __launch_bounds__(1024) void scan_kernel(
    const int* __restrict__ counts, int* __restrict__ offsets) {
  __shared__ int part[1024];
  int tid = threadIdx.x;
  const int CH = 16;  // 1024*16 = 16384 >= 16001
  int base = tid * CH;
  int loc[CH];
  int s = 0;
#pragma unroll
  for (int i = 0; i < CH; ++i) {
    int idx = base + i;
    int c = (idx < NN) ? counts[idx] : 0;
    loc[i] = c;
    s += c;
  }
  part[tid] = s;
  __syncthreads();
  for (int off = 1; off < 1024; off <<= 1) {
    int t = part[tid];
    int add = (tid >= off) ? part[tid - off] : 0;
    __syncthreads();
    part[tid] = t + add;
    __syncthreads();
  }
  int pre = (tid > 0) ? part[tid - 1] : 0;
#pragma unroll
  for (int i = 0; i < CH; ++i) {
    int idx = base + i;
    if (idx <= NN) offsets[idx] = pre;
    pre += loc[i];
  }
}

__global__ __launch_bounds__(256) void fill_kernel(
    const int* __restrict__ recv, const int* __restrict__ offsets,
    int* __restrict__ cursor, int* __restrict__ edge_list) {
  int e = blockIdx.x * 256 + threadIdx.x;
  if (e < EE) {
    int r = recv[e];
    int pos = atomicAdd(&cursor[r], 1);
    edge_list[offsets[r] + pos] = e;
  }
}

// gather: one wave per node (4 nodes per wave sequentially), lane = channel u
// macc[n][cm][u], cm = conv*9 + m
__global__ __launch_bounds__(256) void gather_kernel(
    const float* __restrict__ h, const float* __restrict__ ef,
    const float* __restrict__ ear, const float* __restrict__ eai,
    const int* __restrict__ senders, const int* __restrict__ species,
    const int* __restrict__ offsets, const int* __restrict__ edge_list,
    const float* __restrict__ W_tpw, float* __restrict__ macc) {
  __shared__ float sWt[AA * RR * 3 * 64];  // 15360 floats = 61440 B
  for (int k = threadIdx.x; k < AA * RR * 3 * 64; k += 256) sWt[k] = W_tpw[k];
  __syncthreads();
  int wid = __builtin_amdgcn_readfirstlane(threadIdx.x >> 6);
  int lane = threadIdx.x & 63;
  for (int j = 0; j < 4; ++j) {
    int n = blockIdx.x * 16 + wid * 4 + j;
    float accR[9], accI[9];
#pragma unroll
    for (int m = 0; m < 9; ++m) { accR[m] = 0.f; accI[m] = 0.f; }
    int beg = offsets[n], end = offsets[n + 1];
    for (int idx = beg; idx < end; ++idx) {
      int e = edge_list[idx];   // uniform
      int s = senders[e];       // uniform
      int a = species[s];       // uniform
      float xs = h[(size_t)s * 64 + lane];  // coalesced
      const float* efp = ef + (size_t)e * RR;
      const float* wt = sWt + a * (RR * 3 * 64);
      float t0 = 0.f, t1 = 0.f, t2 = 0.f;
#pragma unroll
      for (int r = 0; r < RR; ++r) {
        float f = efp[r];  // wave-uniform
        t0 = fmaf(f, wt[r * 192 + lane], t0);
        t1 = fmaf(f, wt[r * 192 + 64 + lane], t1);
        t2 = fmaf(f, wt[r * 192 + 128 + lane], t2);
      }
      t0 *= xs; t1 *= xs; t2 *= xs;
      const float* er = ear + (size_t)e * 9;
      const float* ei = eai + (size_t)e * 9;
      accR[0] = fmaf(t0, er[0], accR[0]);
      accI[0] = fmaf(t0, ei[0], accI[0]);
#pragma unroll
      for (int m = 1; m < 4; ++m) {
        accR[m] = fmaf(t1, er[m], accR[m]);
        accI[m] = fmaf(t1, ei[m], accI[m]);
      }
#pragma unroll
      for (int m = 4; m < 9; ++m) {
        accR[m] = fmaf(t2, er[m], accR[m]);
        accI[m] = fmaf(t2, ei[m], accI[m]);
      }
    }
    float* mp = macc + (size_t)n * 1152;
#pragma unroll
    for (int m = 0; m < 9; ++m) {
      mp[m * 64 + lane] = accR[m];
      mp[(9 + m) * 64 + lane] = accI[m];
    }
  }
}

// linear: out[n,v,m] = sum_u macc[n][cm][u] * W_lin[l(m)][u][v] * (1/8/16)
// one wave handles 4 nodes; W column for lane held in 64 VGPRs per l
__global__ __launch_bounds__(256) void lin_kernel(
    const float* __restrict__ macc, const float* __restrict__ W_lin,
    float* __restrict__ out) {
  int wid = __builtin_amdgcn_readfirstlane(threadIdx.x >> 6);
  int lane = threadIdx.x & 63;
  int wbase = (blockIdx.x * 4 + wid) * 4;
  const float SCL = 0.0078125f;  // (1/sqrt(64))/16
#pragma unroll
  for (int l = 0; l < 3; ++l) {
    float wreg[64];
#pragma unroll
    for (int u = 0; u < 64; ++u) wreg[u] = W_lin[l * 4096 + u * 64 + lane];
    const int m0 = (l == 0) ? 0 : (l == 1) ? 1 : 4;
    const int m1 = (l == 0) ? 1 : (l == 1) ? 4 : 9;
    for (int j = 0; j < 4; ++j) {
      int n = wbase + j;  // wave-uniform
      const float* Ab = macc + (size_t)n * 1152;
#pragma unroll
      for (int m = m0; m < m1; ++m) {
        const float* Ar = Ab + m * 64;
        const float* Ai = Ab + (9 + m) * 64;
        float sR = 0.f, sI = 0.f;
#pragma unroll
        for (int u = 0; u < 64; ++u) {
          sR = fmaf(Ar[u], wreg[u], sR);  // Ar[u] uniform -> s_load
          sI = fmaf(Ai[u], wreg[u], sI);
        }
        out[(size_t)n * 576 + lane * 9 + m] = sR * SCL;
        out[NC9 + (size_t)n * 576 + lane * 9 + m] = sI * SCL;
      }
    }
  }
}

extern "C" void kernel_launch(void* const* d_in, const int* in_sizes, int n_in,
                              void* d_out, int out_size, void* d_ws, size_t ws_size,
                              hipStream_t stream) {
  const float* node_attrs = (const float*)d_in[0];
  const float* node_feats = (const float*)d_in[1];
  const float* ear        = (const float*)d_in[2];
  const float* eai        = (const float*)d_in[3];
  const float* ef         = (const float*)d_in[4];
  const int*   senders    = (const int*)d_in[5];
  const int*   receivers  = (const int*)d_in[6];
  const float* W_up       = (const float*)d_in[7];
  const float* W_tpw      = (const float*)d_in[8];
  const float* W_lin      = (const float*)d_in[9];
  const float* W_skip     = (const float*)d_in[10];
  float* out = (float*)d_out;

  char* ws = (char*)d_ws;
  float* h        = (float*)(ws + WS_H);
  float* macc     = (float*)(ws + WS_MACC);
  int*   species  = (int*)(ws + WS_SPECIES);
  int*   counts   = (int*)(ws + WS_COUNTS);
  int*   cursor   = (int*)(ws + WS_CURSOR);
  int*   offsets  = (int*)(ws + WS_OFFSETS);
  int*   edgelist = (int*)(ws + WS_EDGELIST);

  // zero counts + cursor (contiguous 128 KB)
  hipMemsetAsync(ws + WS_COUNTS, 0, 128000, stream);

  species_kernel<<<63, 256, 0, stream>>>(node_attrs, species);
  node_kernel<<<4000, 256, 0, stream>>>(node_feats, species, W_up, W_skip, h, out);
  hist_kernel<<<1000, 256, 0, stream>>>(receivers, counts);
  scan_kernel<<<1, 1024, 0, stream>>>(counts, offsets);
  fill_kernel<<<1000, 256, 0, stream>>>(receivers, offsets, cursor, edgelist);
  gather_kernel<<<1000, 256, 0, stream>>>(h, ef, ear, eai, senders, species,
                                          offsets, edgelist, W_tpw, macc);
  lin_kernel<<<1000, 256, 0, stream>>>(macc, W_lin, out);
}

// Round 2
// 457.433 us; speedup vs baseline: 1.1753x; 1.1753x over previous
//
#include <hip/hip_runtime.h>
#include <hip/hip_bf16.h>

#define NN 16000
#define EE 256000
#define CC 64
#define AA 10
#define RR 8
#define NC9 9216000      // N*C*9
#define SC_OFF 18432000  // 2*N*C*9

// ---------------- workspace layout (bytes) ----------------
#define WS_H        0
#define WS_MACC     4096000
#define WS_SPECIES  77824000
#define WS_COUNTS   77888000
#define WS_CURSOR   77952000
#define WS_OFFSETS  78016000
#define WS_EDGELIST 78080256
#define WS_PKLIST   79104256
// end: 80,128,256 bytes

__global__ __launch_bounds__(256) void species_kernel(
    const float* __restrict__ attrs, int* __restrict__ species) {
  int i = blockIdx.x * 256 + threadIdx.x;
  if (i >= NN) return;
  const float* p = attrs + (size_t)i * AA;
  int sp = 0;
#pragma unroll
  for (int a = 1; a < AA; ++a)
    if (p[a] > 0.5f) sp = a;
  species[i] = sp;
}

// h = (nf @ W_up)/8 ; sc = (nf . W_skip[:,a,:])/sqrt(640)
__global__ __launch_bounds__(256) void node_kernel(
    const float* __restrict__ nf, const int* __restrict__ species,
    const float* __restrict__ W_up, const float* __restrict__ W_skip,
    float* __restrict__ h, float* __restrict__ out) {
  int wid = __builtin_amdgcn_readfirstlane(threadIdx.x >> 6);
  int lane = threadIdx.x & 63;
  int n = blockIdx.x * 4 + wid;
  int a = species[n];
  const float* nfp = nf + (size_t)n * 64;
  const float* wsk = W_skip + (size_t)a * 64;  // + u*640 + lane
  float hacc = 0.f, sacc = 0.f;
#pragma unroll
  for (int u = 0; u < 64; ++u) {
    float x = nfp[u];  // wave-uniform -> scalar load
    hacc = fmaf(x, W_up[u * 64 + lane], hacc);
    sacc = fmaf(x, wsk[u * 640 + lane], sacc);
  }
  h[(size_t)n * 64 + lane] = hacc * 0.125f;
  out[SC_OFF + (size_t)n * 64 + lane] = sacc * 0.03952847075210474f;
}

__global__ __launch_bounds__(256) void hist_kernel(
    const int* __restrict__ recv, int* __restrict__ counts) {
  int e = blockIdx.x * 256 + threadIdx.x;
  if (e < EE) atomicAdd(&counts[recv[e]], 1);
}

// single-block exclusive scan of counts[N] -> offsets[N+1]
__global__ __launch_bounds__(1024) void scan_kernel(
    const int* __restrict__ counts, int* __restrict__ offsets) {
  __shared__ int part[1024];
  int tid = threadIdx.x;
  const int CH = 16;  // 1024*16 = 16384 >= 16001
  int base = tid * CH;
  int loc[CH];
  int s = 0;
#pragma unroll
  for (int i = 0; i < CH; ++i) {
    int idx = base + i;
    int c = (idx < NN) ? counts[idx] : 0;
    loc[i] = c;
    s += c;
  }
  part[tid] = s;
  __syncthreads();
  for (int off = 1; off < 1024; off <<= 1) {
    int t = part[tid];
    int add = (tid >= off) ? part[tid - off] : 0;
    __syncthreads();
    part[tid] = t + add;
    __syncthreads();
  }
  int pre = (tid > 0) ? part[tid - 1] : 0;
#pragma unroll
  for (int i = 0; i < CH; ++i) {
    int idx = base + i;
    if (idx <= NN) offsets[idx] = pre;
    pre += loc[i];
  }
}

// CSR fill + precompute packed (sender | species<<20) per slot
__global__ __launch_bounds__(256) void fill_kernel(
    const int* __restrict__ recv, const int* __restrict__ senders,
    const int* __restrict__ species, const int* __restrict__ offsets,
    int* __restrict__ cursor, int* __restrict__ edge_list,
    int* __restrict__ pk_list) {
  int e = blockIdx.x * 256 + threadIdx.x;
  if (e < EE) {
    int r = recv[e];
    int pos = atomicAdd(&cursor[r], 1);
    int slot = offsets[r] + pos;
    edge_list[slot] = e;
    int s = senders[e];
    int a = species[s];
    pk_list[slot] = s | (a << 20);
  }
}

// gather: ONE node per wave, 8 waves (512 thr) per block sharing one sWt copy
// -> 2 blocks/CU by LDS = 16 waves/CU. lane = channel u.
// macc[n][cm][u], cm = conv*9 + m
__global__ __launch_bounds__(512) void gather_kernel(
    const float* __restrict__ h, const float* __restrict__ ef,
    const float* __restrict__ ear, const float* __restrict__ eai,
    const int* __restrict__ offsets, const int* __restrict__ edge_list,
    const int* __restrict__ pk_list, const float* __restrict__ W_tpw,
    float* __restrict__ macc) {
  __shared__ float sWt[AA * RR * 3 * 64];  // 15360 floats = 61440 B
  for (int k = threadIdx.x; k < AA * RR * 3 * 64; k += 512) sWt[k] = W_tpw[k];
  __syncthreads();
  int wid = __builtin_amdgcn_readfirstlane(threadIdx.x >> 6);
  int lane = threadIdx.x & 63;
  int n = blockIdx.x * 8 + wid;  // wave-uniform
  float accR[9], accI[9];
#pragma unroll
  for (int m = 0; m < 9; ++m) { accR[m] = 0.f; accI[m] = 0.f; }
  int beg = offsets[n], end = offsets[n + 1];
  int e = 0, pk = 0;
  if (beg < end) { e = edge_list[beg]; pk = pk_list[beg]; }
  for (int idx = beg; idx < end; ++idx) {
    // prefetch next edge's indirection while current edge computes
    int e_n = 0, pk_n = 0;
    if (idx + 1 < end) { e_n = edge_list[idx + 1]; pk_n = pk_list[idx + 1]; }
    int s = pk & 0xFFFFF;       // uniform
    int a = pk >> 20;           // uniform
    float xs = h[(size_t)s * 64 + lane];   // coalesced vector load
    const float* efp = ef + (size_t)e * RR;   // uniform -> s_load
    const float* wt = sWt + a * (RR * 3 * 64);
    float t0 = 0.f, t1 = 0.f, t2 = 0.f;
#pragma unroll
    for (int r = 0; r < RR; ++r) {
      float f = efp[r];  // wave-uniform
      t0 = fmaf(f, wt[r * 192 + lane], t0);
      t1 = fmaf(f, wt[r * 192 + 64 + lane], t1);
      t2 = fmaf(f, wt[r * 192 + 128 + lane], t2);
    }
    t0 *= xs; t1 *= xs; t2 *= xs;
    const float* er = ear + (size_t)e * 9;  // uniform -> s_load
    const float* ei = eai + (size_t)e * 9;
    accR[0] = fmaf(t0, er[0], accR[0]);
    accI[0] = fmaf(t0, ei[0], accI[0]);
#pragma unroll
    for (int m = 1; m < 4; ++m) {
      accR[m] = fmaf(t1, er[m], accR[m]);
      accI[m] = fmaf(t1, ei[m], accI[m]);
    }
#pragma unroll
    for (int m = 4; m < 9; ++m) {
      accR[m] = fmaf(t2, er[m], accR[m]);
      accI[m] = fmaf(t2, ei[m], accI[m]);
    }
    e = e_n; pk = pk_n;
  }
  float* mp = macc + (size_t)n * 1152;
#pragma unroll
  for (int m = 0; m < 9; ++m) {
    mp[m * 64 + lane] = accR[m];
    mp[(9 + m) * 64 + lane] = accI[m];
  }
}

// linear: out[n,v,m] = sum_u macc[n][cm][u] * W_lin[l(m)][u][v] * (1/8/16)
__global__ __launch_bounds__(256) void lin_kernel(
    const float* __restrict__ macc, const float* __restrict__ W_lin,
    float* __restrict__ out) {
  int wid = __builtin_amdgcn_readfirstlane(threadIdx.x >> 6);
  int lane = threadIdx.x & 63;
  int wbase = (blockIdx.x * 4 + wid) * 4;
  const float SCL = 0.0078125f;  // (1/sqrt(64))/16
#pragma unroll
  for (int l = 0; l < 3; ++l) {
    float wreg[64];
#pragma unroll
    for (int u = 0; u < 64; ++u) wreg[u] = W_lin[l * 4096 + u * 64 + lane];
    const int m0 = (l == 0) ? 0 : (l == 1) ? 1 : 4;
    const int m1 = (l == 0) ? 1 : (l == 1) ? 4 : 9;
    for (int j = 0; j < 4; ++j) {
      int n = wbase + j;  // wave-uniform
      const float* Ab = macc + (size_t)n * 1152;
#pragma unroll
      for (int m = m0; m < m1; ++m) {
        const float* Ar = Ab + m * 64;
        const float* Ai = Ab + (9 + m) * 64;
        float sR = 0.f, sI = 0.f;
#pragma unroll
        for (int u = 0; u < 64; ++u) {
          sR = fmaf(Ar[u], wreg[u], sR);  // Ar[u] uniform -> s_load
          sI = fmaf(Ai[u], wreg[u], sI);
        }
        out[(size_t)n * 576 + lane * 9 + m] = sR * SCL;
        out[NC9 + (size_t)n * 576 + lane * 9 + m] = sI * SCL;
      }
    }
  }
}

extern "C" void kernel_launch(void* const* d_in, const int* in_sizes, int n_in,
                              void* d_out, int out_size, void* d_ws, size_t ws_size,
                              hipStream_t stream) {
  const float* node_attrs = (const float*)d_in[0];
  const float* node_feats = (const float*)d_in[1];
  const float* ear        = (const float*)d_in[2];
  const float* eai        = (const float*)d_in[3];
  const float* ef         = (const float*)d_in[4];
  const int*   senders    = (const int*)d_in[5];
  const int*   receivers  = (const int*)d_in[6];
  const float* W_up       = (const float*)d_in[7];
  const float* W_tpw      = (const float*)d_in[8];
  const float* W_lin      = (const float*)d_in[9];
  const float* W_skip     = (const float*)d_in[10];
  float* out = (float*)d_out;

  char* ws = (char*)d_ws;
  float* h        = (float*)(ws + WS_H);
  float* macc     = (float*)(ws + WS_MACC);
  int*   species  = (int*)(ws + WS_SPECIES);
  int*   counts   = (int*)(ws + WS_COUNTS);
  int*   cursor   = (int*)(ws + WS_CURSOR);
  int*   offsets  = (int*)(ws + WS_OFFSETS);
  int*   edgelist = (int*)(ws + WS_EDGELIST);
  int*   pklist   = (int*)(ws + WS_PKLIST);

  // zero counts + cursor (contiguous 128 KB)
  hipMemsetAsync(ws + WS_COUNTS, 0, 128000, stream);

  species_kernel<<<63, 256, 0, stream>>>(node_attrs, species);
  node_kernel<<<4000, 256, 0, stream>>>(node_feats, species, W_up, W_skip, h, out);
  hist_kernel<<<1000, 256, 0, stream>>>(receivers, counts);
  scan_kernel<<<1, 1024, 0, stream>>>(counts, offsets);
  fill_kernel<<<1000, 256, 0, stream>>>(receivers, senders, species, offsets,
                                        cursor, edgelist, pklist);
  gather_kernel<<<2000, 512, 0, stream>>>(h, ef, ear, eai, offsets, edgelist,
                                          pklist, W_tpw, macc);
  lin_kernel<<<1000, 256, 0, stream>>>(macc, W_lin, out);
}

// Round 4
// 447.783 us; speedup vs baseline: 1.2006x; 1.0216x over previous
//
#include <hip/hip_runtime.h>
#include <hip/hip_bf16.h>

#define NN 16000
#define EE 256000
#define CC 64
#define AA 10
#define RR 8
#define NC9 9216000      // N*C*9
#define SC_OFF 18432000  // 2*N*C*9

// ---------------- workspace layout (bytes) ----------------
#define WS_H        0
#define WS_SPECIES  77824000
#define WS_COUNTS   77888000
#define WS_CURSOR   77952000
#define WS_OFFSETS  78016000
#define WS_EDGELIST 78080256
#define WS_PKLIST   79104256
// end: 80,128,256 bytes

__global__ __launch_bounds__(256) void species_kernel(
    const float* __restrict__ attrs, int* __restrict__ species) {
  int i = blockIdx.x * 256 + threadIdx.x;
  if (i >= NN) return;
  const float* p = attrs + (size_t)i * AA;
  int sp = 0;
#pragma unroll
  for (int a = 1; a < AA; ++a)
    if (p[a] > 0.5f) sp = a;
  species[i] = sp;
}

// h = (nf @ W_up)/8 ; sc = (nf . W_skip[:,a,:])/sqrt(640)
__global__ __launch_bounds__(256) void node_kernel(
    const float* __restrict__ nf, const int* __restrict__ species,
    const float* __restrict__ W_up, const float* __restrict__ W_skip,
    float* __restrict__ h, float* __restrict__ out) {
  int wid = __builtin_amdgcn_readfirstlane(threadIdx.x >> 6);
  int lane = threadIdx.x & 63;
  int n = blockIdx.x * 4 + wid;
  int a = species[n];
  const float* nfp = nf + (size_t)n * 64;
  const float* wsk = W_skip + (size_t)a * 64;  // + u*640 + lane
  float hacc = 0.f, sacc = 0.f;
#pragma unroll
  for (int u = 0; u < 64; ++u) {
    float x = nfp[u];  // wave-uniform -> scalar load
    hacc = fmaf(x, W_up[u * 64 + lane], hacc);
    sacc = fmaf(x, wsk[u * 640 + lane], sacc);
  }
  h[(size_t)n * 64 + lane] = hacc * 0.125f;
  out[SC_OFF + (size_t)n * 64 + lane] = sacc * 0.03952847075210474f;
}

__global__ __launch_bounds__(256) void hist_kernel(
    const int* __restrict__ recv, int* __restrict__ counts) {
  int e = blockIdx.x * 256 + threadIdx.x;
  if (e < EE) atomicAdd(&counts[recv[e]], 1);
}

// single-block exclusive scan of counts[N] -> offsets[N+1]
__global__ __launch_bounds__(1024) void scan_kernel(
    const int* __restrict__ counts, int* __restrict__ offsets) {
  __shared__ int part[1024];
  int tid = threadIdx.x;
  const int CH = 16;  // 1024*16 = 16384 >= 16001
  int base = tid * CH;
  int loc[CH];
  int s = 0;
#pragma unroll
  for (int i = 0; i < CH; ++i) {
    int idx = base + i;
    int c = (idx < NN) ? counts[idx] : 0;
    loc[i] = c;
    s += c;
  }
  part[tid] = s;
  __syncthreads();
  for (int off = 1; off < 1024; off <<= 1) {
    int t = part[tid];
    int add = (tid >= off) ? part[tid - off] : 0;
    __syncthreads();
    part[tid] = t + add;
    __syncthreads();
  }
  int pre = (tid > 0) ? part[tid - 1] : 0;
#pragma unroll
  for (int i = 0; i < CH; ++i) {
    int idx = base + i;
    if (idx <= NN) offsets[idx] = pre;
    pre += loc[i];
  }
}

// CSR fill + precompute packed (sender | species<<20) per slot
__global__ __launch_bounds__(256) void fill_kernel(
    const int* __restrict__ recv, const int* __restrict__ senders,
    const int* __restrict__ species, const int* __restrict__ offsets,
    int* __restrict__ cursor, int* __restrict__ edge_list,
    int* __restrict__ pk_list) {
  int e = blockIdx.x * 256 + threadIdx.x;
  if (e < EE) {
    int r = recv[e];
    int pos = atomicAdd(&cursor[r], 1);
    int slot = offsets[r] + pos;
    edge_list[slot] = e;
    int s = senders[e];
    int a = species[s];
    pk_list[slot] = s | (a << 20);
  }
}

// FUSED gather + per-l linear. One node per wave, 8 waves/block.
// LDS: W_tpw staged (61440 B) during edge phase; after a block barrier the
// same region is reused as per-wave transpose scratch:
//   [wid*1280 .. +1280) : interleaved acc  [u][20]  (cm = 2*m + conv)
//   [10240 + wid*576)   : final staging    [v*9+m]  for coalesced out writes
__global__ __launch_bounds__(512) void fused_kernel(
    const float* __restrict__ h, const float* __restrict__ ef,
    const float* __restrict__ ear, const float* __restrict__ eai,
    const int* __restrict__ offsets, const int* __restrict__ edge_list,
    const int* __restrict__ pk_list, const float* __restrict__ W_tpw,
    const float* __restrict__ W_lin, float* __restrict__ out) {
  __shared__ float lds[AA * RR * 3 * 64];  // 15360 floats = 61440 B
  for (int k = threadIdx.x; k < AA * RR * 3 * 64; k += 512) lds[k] = W_tpw[k];
  __syncthreads();
  int wid = __builtin_amdgcn_readfirstlane(threadIdx.x >> 6);
  int lane = threadIdx.x & 63;
  int n = blockIdx.x * 8 + wid;  // wave-uniform
  float accR[9], accI[9];
#pragma unroll
  for (int m = 0; m < 9; ++m) { accR[m] = 0.f; accI[m] = 0.f; }
  int beg = offsets[n], end = offsets[n + 1];
  int e = 0, pk = 0;
  if (beg < end) { e = edge_list[beg]; pk = pk_list[beg]; }
  for (int idx = beg; idx < end; ++idx) {
    int e_n = 0, pk_n = 0;
    if (idx + 1 < end) { e_n = edge_list[idx + 1]; pk_n = pk_list[idx + 1]; }
    int s = pk & 0xFFFFF;       // uniform
    int a = pk >> 20;           // uniform
    float xs = h[(size_t)s * 64 + lane];      // coalesced vector load
    const float* efp = ef + (size_t)e * RR;   // uniform -> s_load
    const float* wt = lds + a * (RR * 3 * 64);
    float t0 = 0.f, t1 = 0.f, t2 = 0.f;
#pragma unroll
    for (int r = 0; r < RR; ++r) {
      float f = efp[r];  // wave-uniform
      t0 = fmaf(f, wt[r * 192 + lane], t0);
      t1 = fmaf(f, wt[r * 192 + 64 + lane], t1);
      t2 = fmaf(f, wt[r * 192 + 128 + lane], t2);
    }
    t0 *= xs; t1 *= xs; t2 *= xs;
    const float* er = ear + (size_t)e * 9;  // uniform -> s_load
    const float* ei = eai + (size_t)e * 9;
    accR[0] = fmaf(t0, er[0], accR[0]);
    accI[0] = fmaf(t0, ei[0], accI[0]);
#pragma unroll
    for (int m = 1; m < 4; ++m) {
      accR[m] = fmaf(t1, er[m], accR[m]);
      accI[m] = fmaf(t1, ei[m], accI[m]);
    }
#pragma unroll
    for (int m = 4; m < 9; ++m) {
      accR[m] = fmaf(t2, er[m], accR[m]);
      accI[m] = fmaf(t2, ei[m], accI[m]);
    }
    e = e_n; pk = pk_n;
  }
  __syncthreads();  // all waves done reading W_tpw; reuse LDS as scratch

  // ---- transpose stage: lane (=u) writes its acc, interleaved R/I ----
  float* sc = &lds[wid * 1280];  // [u][20]
#pragma unroll
  for (int m = 0; m < 9; ++m) {
    sc[lane * 20 + 2 * m]     = accR[m];
    sc[lane * 20 + 2 * m + 1] = accI[m];
  }
  // ---- channel mix: lane (=v), out[v][m] = sum_u acc[u][m] * W[l][u][v] ----
  const float SCL = 0.0078125f;  // (1/sqrt(64))/16
  float outR[9], outI[9];
#pragma unroll
  for (int m = 0; m < 9; ++m) { outR[m] = 0.f; outI[m] = 0.f; }
  float* stg = &lds[10240 + wid * 576];  // [v*9+m]
#pragma unroll
  for (int l = 0; l < 3; ++l) {
    const int m0 = (l == 0) ? 0 : (l == 1) ? 1 : 4;
    const int m1 = (l == 0) ? 1 : (l == 1) ? 4 : 9;
    float wreg[64];
#pragma unroll
    for (int u = 0; u < 64; ++u) wreg[u] = W_lin[l * 4096 + u * 64 + lane];
#pragma unroll
    for (int u = 0; u < 64; ++u) {
      const float* su = sc + u * 20;
#pragma unroll
      for (int m = m0; m < m1; ++m) {
        outR[m] = fmaf(su[2 * m], wreg[u], outR[m]);
        outI[m] = fmaf(su[2 * m + 1], wreg[u], outI[m]);
      }
    }
  }
  // ---- coalesced output: stage R, write; stage I, write ----
#pragma unroll
  for (int m = 0; m < 9; ++m) stg[lane * 9 + m] = outR[m] * SCL;
  __builtin_amdgcn_s_waitcnt(0);  // lgkmcnt(0): same-wave LDS ordering
#pragma unroll
  for (int k = 0; k < 9; ++k)
    out[(size_t)n * 576 + k * 64 + lane] = stg[k * 64 + lane];
#pragma unroll
  for (int m = 0; m < 9; ++m) stg[lane * 9 + m] = outI[m] * SCL;
  __builtin_amdgcn_s_waitcnt(0);
#pragma unroll
  for (int k = 0; k < 9; ++k)
    out[NC9 + (size_t)n * 576 + k * 64 + lane] = stg[k * 64 + lane];
}

extern "C" void kernel_launch(void* const* d_in, const int* in_sizes, int n_in,
                              void* d_out, int out_size, void* d_ws, size_t ws_size,
                              hipStream_t stream) {
  const float* node_attrs = (const float*)d_in[0];
  const float* node_feats = (const float*)d_in[1];
  const float* ear        = (const float*)d_in[2];
  const float* eai        = (const float*)d_in[3];
  const float* ef         = (const float*)d_in[4];
  const int*   senders    = (const int*)d_in[5];
  const int*   receivers  = (const int*)d_in[6];
  const float* W_up       = (const float*)d_in[7];
  const float* W_tpw      = (const float*)d_in[8];
  const float* W_lin      = (const float*)d_in[9];
  const float* W_skip     = (const float*)d_in[10];
  float* out = (float*)d_out;

  char* ws = (char*)d_ws;
  float* h        = (float*)(ws + WS_H);
  int*   species  = (int*)(ws + WS_SPECIES);
  int*   counts   = (int*)(ws + WS_COUNTS);
  int*   cursor   = (int*)(ws + WS_CURSOR);
  int*   offsets  = (int*)(ws + WS_OFFSETS);
  int*   edgelist = (int*)(ws + WS_EDGELIST);
  int*   pklist   = (int*)(ws + WS_PKLIST);

  // zero counts + cursor (contiguous 128 KB)
  hipMemsetAsync(ws + WS_COUNTS, 0, 128000, stream);

  species_kernel<<<63, 256, 0, stream>>>(node_attrs, species);
  node_kernel<<<4000, 256, 0, stream>>>(node_feats, species, W_up, W_skip, h, out);
  hist_kernel<<<1000, 256, 0, stream>>>(receivers, counts);
  scan_kernel<<<1, 1024, 0, stream>>>(counts, offsets);
  fill_kernel<<<1000, 256, 0, stream>>>(receivers, senders, species, offsets,
                                        cursor, edgelist, pklist);
  fused_kernel<<<2000, 512, 0, stream>>>(h, ef, ear, eai, offsets, edgelist,
                                         pklist, W_tpw, W_lin, out);
}

// Round 5
// 351.940 us; speedup vs baseline: 1.5276x; 1.2723x over previous
//
#include <hip/hip_runtime.h>
#include <hip/hip_bf16.h>

#define NN 16000
#define EE 256000
#define CC 64
#define AA 10
#define RR 8
#define NC9 9216000      // N*C*9
#define SC_OFF 18432000  // 2*N*C*9

// ---------------- workspace layout (bytes) ----------------
// h:       [N][64] f32                      0 .. 4,096,000
// blk:     [E+2][28] dwords (112 B each)    4,096,000 .. 32,768,224
// species: [N] i32                          32,768,256 ..
// counts:  [N] i32                          32,832,256 ..
// cursor:  [N] i32                          32,896,256 ..
// offsets: [N+1] i32                        32,960,256 ..
#define WS_H        0
#define WS_BLK      4096000
#define WS_SPECIES  32768256
#define WS_COUNTS   32832256
#define WS_CURSOR   32896256
#define WS_OFFSETS  32960256

__global__ __launch_bounds__(256) void species_kernel(
    const float* __restrict__ attrs, int* __restrict__ species) {
  int i = blockIdx.x * 256 + threadIdx.x;
  if (i >= NN) return;
  const float* p = attrs + (size_t)i * AA;
  int sp = 0;
#pragma unroll
  for (int a = 1; a < AA; ++a)
    if (p[a] > 0.5f) sp = a;
  species[i] = sp;
}

// h = (nf @ W_up)/8 ; sc = (nf . W_skip[:,a,:])/sqrt(640)
__global__ __launch_bounds__(256) void node_kernel(
    const float* __restrict__ nf, const int* __restrict__ species,
    const float* __restrict__ W_up, const float* __restrict__ W_skip,
    float* __restrict__ h, float* __restrict__ out) {
  int wid = __builtin_amdgcn_readfirstlane(threadIdx.x >> 6);
  int lane = threadIdx.x & 63;
  int n = blockIdx.x * 4 + wid;
  int a = species[n];
  const float* nfp = nf + (size_t)n * 64;
  const float* wsk = W_skip + (size_t)a * 64;  // + u*640 + lane
  float hacc = 0.f, sacc = 0.f;
#pragma unroll
  for (int u = 0; u < 64; ++u) {
    float x = nfp[u];  // wave-uniform -> scalar load
    hacc = fmaf(x, W_up[u * 64 + lane], hacc);
    sacc = fmaf(x, wsk[u * 640 + lane], sacc);
  }
  h[(size_t)n * 64 + lane] = hacc * 0.125f;
  out[SC_OFF + (size_t)n * 64 + lane] = sacc * 0.03952847075210474f;
}

__global__ __launch_bounds__(256) void hist_kernel(
    const int* __restrict__ recv, int* __restrict__ counts) {
  int e = blockIdx.x * 256 + threadIdx.x;
  if (e < EE) atomicAdd(&counts[recv[e]], 1);
}

// single-block exclusive scan of counts[N] -> offsets[N+1]
__global__ __launch_bounds__(1024) void scan_kernel(
    const int* __restrict__ counts, int* __restrict__ offsets) {
  __shared__ int part[1024];
  int tid = threadIdx.x;
  const int CH = 16;  // 1024*16 = 16384 >= 16001
  int base = tid * CH;
  int loc[CH];
  int s = 0;
#pragma unroll
  for (int i = 0; i < CH; ++i) {
    int idx = base + i;
    int c = (idx < NN) ? counts[idx] : 0;
    loc[i] = c;
    s += c;
  }
  part[tid] = s;
  __syncthreads();
  for (int off = 1; off < 1024; off <<= 1) {
    int t = part[tid];
    int add = (tid >= off) ? part[tid - off] : 0;
    __syncthreads();
    part[tid] = t + add;
    __syncthreads();
  }
  int pre = (tid > 0) ? part[tid - 1] : 0;
#pragma unroll
  for (int i = 0; i < CH; ++i) {
    int idx = base + i;
    if (idx <= NN) offsets[idx] = pre;
    pre += loc[i];
  }
}

// CSR fill: build packed 112-B per-slot edge block:
// dw0 = pk = s|(a<<20); dw1-8 = ef[0..7]; dw9-17 = er[0..8]; dw18-26 = ei[0..8]; dw27 pad
__global__ __launch_bounds__(256) void fill_kernel(
    const int* __restrict__ recv, const int* __restrict__ senders,
    const int* __restrict__ species, const int* __restrict__ offsets,
    int* __restrict__ cursor, const float* __restrict__ ef,
    const float* __restrict__ ear, const float* __restrict__ eai,
    float* __restrict__ blk) {
  int e = blockIdx.x * 256 + threadIdx.x;
  if (e >= EE) return;
  int r = recv[e];
  int pos = atomicAdd(&cursor[r], 1);
  int slot = offsets[r] + pos;
  int s = senders[e];
  int a = species[s];
  const float* efp = ef + (size_t)e * 8;
  const float* erp = ear + (size_t)e * 9;
  const float* eip = eai + (size_t)e * 9;
  float4* dst = (float4*)(blk + (size_t)slot * 28);
  float4 q;
  q.x = __int_as_float(s | (a << 20)); q.y = efp[0]; q.z = efp[1]; q.w = efp[2];
  dst[0] = q;
  q.x = efp[3]; q.y = efp[4]; q.z = efp[5]; q.w = efp[6];
  dst[1] = q;
  q.x = efp[7]; q.y = erp[0]; q.z = erp[1]; q.w = erp[2];
  dst[2] = q;
  q.x = erp[3]; q.y = erp[4]; q.z = erp[5]; q.w = erp[6];
  dst[3] = q;
  q.x = erp[7]; q.y = erp[8]; q.z = eip[0]; q.w = eip[1];
  dst[4] = q;
  q.x = eip[2]; q.y = eip[3]; q.z = eip[4]; q.w = eip[5];
  dst[5] = q;
  q.x = eip[6]; q.y = eip[7]; q.z = eip[8]; q.w = 0.f;
  dst[6] = q;
}

#define RL(V, L) __builtin_amdgcn_readlane((V), (L))
#define RLF(V, L) __int_as_float(__builtin_amdgcn_readlane((V), (L)))

// one EDGE: BLK = pair dwords (lane-distributed), OFF = 0 or 28, XS = h[s][lane]
#define EDGE(BLK, OFF, XS) do {                                            \
  float efs[8], ers[9], eis[9];                                            \
  _Pragma("unroll") for (int i_ = 0; i_ < 8; ++i_)                         \
    efs[i_] = RLF((BLK), (OFF) + 1 + i_);                                  \
  _Pragma("unroll") for (int i_ = 0; i_ < 9; ++i_)                         \
    ers[i_] = RLF((BLK), (OFF) + 9 + i_);                                  \
  _Pragma("unroll") for (int i_ = 0; i_ < 9; ++i_)                         \
    eis[i_] = RLF((BLK), (OFF) + 18 + i_);                                 \
  int a_ = RL((BLK), (OFF)) >> 20;                                         \
  const float4* wp_ = (const float4*)(lds + a_ * 1792 + lane * 28);        \
  float4 w0_ = wp_[gpi[0]], w1_ = wp_[gpi[1]], w2_ = wp_[gpi[2]];          \
  float4 w3_ = wp_[gpi[3]], w4_ = wp_[gpi[4]], w5_ = wp_[gpi[5]];          \
  const float wv_[24] = {w0_.x, w0_.y, w0_.z, w0_.w, w1_.x, w1_.y, w1_.z,  \
                         w1_.w, w2_.x, w2_.y, w2_.z, w2_.w, w3_.x, w3_.y,  \
                         w3_.z, w3_.w, w4_.x, w4_.y, w4_.z, w4_.w, w5_.x,  \
                         w5_.y, w5_.z, w5_.w};                             \
  float t0_ = 0.f, t1_ = 0.f, t2_ = 0.f;                                   \
  _Pragma("unroll") for (int r_ = 0; r_ < 8; ++r_) {                       \
    t0_ = fmaf(efs[r_], wv_[r_ * 3 + 0], t0_);                             \
    t1_ = fmaf(efs[r_], wv_[r_ * 3 + 1], t1_);                             \
    t2_ = fmaf(efs[r_], wv_[r_ * 3 + 2], t2_);                             \
  }                                                                        \
  t0_ *= (XS); t1_ *= (XS); t2_ *= (XS);                                   \
  accR[0] = fmaf(t0_, ers[0], accR[0]);                                    \
  accI[0] = fmaf(t0_, eis[0], accI[0]);                                    \
  _Pragma("unroll") for (int m_ = 1; m_ < 4; ++m_) {                       \
    accR[m_] = fmaf(t1_, ers[m_], accR[m_]);                               \
    accI[m_] = fmaf(t1_, eis[m_], accI[m_]);                               \
  }                                                                        \
  _Pragma("unroll") for (int m_ = 4; m_ < 9; ++m_) {                       \
    accR[m_] = fmaf(t2_, ers[m_], accR[m_]);                               \
    accI[m_] = fmaf(t2_, eis[m_], accI[m_]);                               \
  }                                                                        \
} while (0)

// FUSED gather + per-l linear. One node per wave, 8 waves (512 thr)/block.
// LDS: W_tpw swizzled [a][u][28] (71680 B) during edge phase, reused after a
// barrier as per-wave out-staging (wid*1152 floats).
__global__ __launch_bounds__(512, 4) void fused_kernel(
    const float* __restrict__ h, const int* __restrict__ offs,
    const float* __restrict__ blkd, const float* __restrict__ W_tpw,
    const float* __restrict__ W_lin, float* __restrict__ out) {
  __shared__ float lds[17920];  // 71680 B
  // stage W_tpw: (a,r,p,u) -> lds[a*1792 + u*28 + gp*4 + j], k=r*3+p, g=k>>2,
  // j=k&3, gp=(g+(u>>3))%7  (group-rotation kills the 8-lane bank aliasing)
  for (int idx = threadIdx.x; idx < AA * RR * 3 * 64; idx += 512) {
    int a = idx / 1536, rem = idx - a * 1536;
    int r = rem / 192;  int rem2 = rem - r * 192;
    int p = rem2 >> 6;  int u = rem2 & 63;
    int k = r * 3 + p, g = k >> 2, j = k & 3;
    int gp = g + (u >> 3); gp = (gp >= 7) ? gp - 7 : gp;
    lds[a * 1792 + u * 28 + gp * 4 + j] = W_tpw[idx];
  }
  __syncthreads();
  int wid = __builtin_amdgcn_readfirstlane(threadIdx.x >> 6);
  int lane = threadIdx.x & 63;
  int n = blockIdx.x * 8 + wid;  // wave-uniform
  int gpi[6];
#pragma unroll
  for (int g = 0; g < 6; ++g) {
    int t = g + (lane >> 3); gpi[g] = (t >= 7) ? t - 7 : t;
  }
  float accR[9], accI[9];
#pragma unroll
  for (int m = 0; m < 9; ++m) { accR[m] = 0.f; accI[m] = 0.f; }
  int beg = offs[n], end = offs[n + 1];
  int cnt = end - beg;
  if (cnt > 0) {
    const int* base = (const int*)blkd + (size_t)beg * 28;
    int blkP = base[lane];                       // pair 0 (2 edges, 56 dwords)
    int sA = RL(blkP, 0) & 0xFFFFF;  sA = (sA < NN) ? sA : 0;
    int sB = RL(blkP, 28) & 0xFFFFF; sB = (sB < NN) ? sB : 0;
    float xsA = h[(size_t)sA * 64 + lane];
    float xsB = h[(size_t)sB * 64 + lane];
    int pairs = (cnt + 1) >> 1;
    int blkN = (pairs > 1) ? base[56 + lane] : blkP;
    for (int p = 0; p < pairs; ++p) {
      // prefetch chain for pair p+1 (vmcnt(0) wait lands here, covered by
      // the previous iteration's full body)
      float xsA2 = 0.f, xsB2 = 0.f;
      int blkNN = blkN;
      if (p + 1 < pairs) {
        int sA2 = RL(blkN, 0) & 0xFFFFF;  sA2 = (sA2 < NN) ? sA2 : 0;
        int sB2 = RL(blkN, 28) & 0xFFFFF; sB2 = (sB2 < NN) ? sB2 : 0;
        xsA2 = h[(size_t)sA2 * 64 + lane];
        xsB2 = h[(size_t)sB2 * 64 + lane];
        if (p + 2 < pairs) blkNN = base[(size_t)(p + 2) * 56 + lane];
      }
      EDGE(blkP, 0, xsA);
      if (2 * p + 1 < cnt) EDGE(blkP, 28, xsB);
      blkP = blkN; blkN = blkNN; xsA = xsA2; xsB = xsB2;
    }
  }
  __builtin_amdgcn_sched_barrier(0);
  // ---- channel mix via readlane (no LDS): out[v][m] = sum_u acc[u][m]W[u][v]
  float outR[9], outI[9];
#pragma unroll
  for (int m = 0; m < 9; ++m) { outR[m] = 0.f; outI[m] = 0.f; }
  {  // l = 0, m in [0,1)
    float wreg[64];
#pragma unroll
    for (int u = 0; u < 64; ++u) wreg[u] = W_lin[u * 64 + lane];
#pragma unroll
    for (int u = 0; u < 64; ++u) {
      outR[0] = fmaf(RLF(__float_as_int(accR[0]), u), wreg[u], outR[0]);
      outI[0] = fmaf(RLF(__float_as_int(accI[0]), u), wreg[u], outI[0]);
    }
  }
  __builtin_amdgcn_sched_barrier(0);
  {  // l = 1, m in [1,4)
    float wreg[64];
#pragma unroll
    for (int u = 0; u < 64; ++u) wreg[u] = W_lin[4096 + u * 64 + lane];
#pragma unroll
    for (int u = 0; u < 64; ++u) {
#pragma unroll
      for (int m = 1; m < 4; ++m) {
        outR[m] = fmaf(RLF(__float_as_int(accR[m]), u), wreg[u], outR[m]);
        outI[m] = fmaf(RLF(__float_as_int(accI[m]), u), wreg[u], outI[m]);
      }
    }
  }
  __builtin_amdgcn_sched_barrier(0);
  {  // l = 2, m in [4,9)
    float wreg[64];
#pragma unroll
    for (int u = 0; u < 64; ++u) wreg[u] = W_lin[8192 + u * 64 + lane];
#pragma unroll
    for (int u = 0; u < 64; ++u) {
#pragma unroll
      for (int m = 4; m < 9; ++m) {
        outR[m] = fmaf(RLF(__float_as_int(accR[m]), u), wreg[u], outR[m]);
        outI[m] = fmaf(RLF(__float_as_int(accI[m]), u), wreg[u], outI[m]);
      }
    }
  }
  __builtin_amdgcn_sched_barrier(0);
  // ---- staged coalesced output (reuse LDS region after barrier) ----
  __syncthreads();
  const float SCL = 0.0078125f;  // (1/sqrt(64))/16
  float* stg = lds + wid * 1152;
#pragma unroll
  for (int m = 0; m < 9; ++m) {
    stg[lane * 9 + m] = outR[m] * SCL;
    stg[576 + lane * 9 + m] = outI[m] * SCL;
  }
#pragma unroll
  for (int k = 0; k < 9; ++k) {
    out[(size_t)n * 576 + k * 64 + lane] = stg[k * 64 + lane];
    out[NC9 + (size_t)n * 576 + k * 64 + lane] = stg[576 + k * 64 + lane];
  }
}

extern "C" void kernel_launch(void* const* d_in, const int* in_sizes, int n_in,
                              void* d_out, int out_size, void* d_ws, size_t ws_size,
                              hipStream_t stream) {
  const float* node_attrs = (const float*)d_in[0];
  const float* node_feats = (const float*)d_in[1];
  const float* ear        = (const float*)d_in[2];
  const float* eai        = (const float*)d_in[3];
  const float* ef         = (const float*)d_in[4];
  const int*   senders    = (const int*)d_in[5];
  const int*   receivers  = (const int*)d_in[6];
  const float* W_up       = (const float*)d_in[7];
  const float* W_tpw      = (const float*)d_in[8];
  const float* W_lin      = (const float*)d_in[9];
  const float* W_skip     = (const float*)d_in[10];
  float* out = (float*)d_out;

  char* ws = (char*)d_ws;
  float* h        = (float*)(ws + WS_H);
  float* blk      = (float*)(ws + WS_BLK);
  int*   species  = (int*)(ws + WS_SPECIES);
  int*   counts   = (int*)(ws + WS_COUNTS);
  int*   cursor   = (int*)(ws + WS_CURSOR);
  int*   offsets  = (int*)(ws + WS_OFFSETS);

  // zero counts + cursor (contiguous 128 KB)
  hipMemsetAsync(ws + WS_COUNTS, 0, 128000, stream);

  species_kernel<<<63, 256, 0, stream>>>(node_attrs, species);
  node_kernel<<<4000, 256, 0, stream>>>(node_feats, species, W_up, W_skip, h, out);
  hist_kernel<<<1000, 256, 0, stream>>>(receivers, counts);
  scan_kernel<<<1, 1024, 0, stream>>>(counts, offsets);
  fill_kernel<<<1000, 256, 0, stream>>>(receivers, senders, species, offsets,
                                        cursor, ef, ear, eai, blk);
  fused_kernel<<<2000, 512, 0, stream>>>(h, offsets, blk, W_tpw, W_lin, out);
}